// Round 1
// baseline (734.945 us; speedup 1.0000x reference)
//
#include <hip/hip_runtime.h>

#define BB 4
#define CC 128
#define NN 4096
#define CK 32

// ---------------------------------------------------------------------------
// Kernel 1: fused 1x1 conv projections f = Wf x + bf, g = Wg x + bg, v = Wh x + bh
// Grid: (N/64, B), block 256. Stage x tile [128][64] in LDS; each thread owns
// 4 pixels (jq) x 12 output channels (o = og + 16*i).
// ---------------------------------------------------------------------------
__global__ __launch_bounds__(256) void proj_kernel(
    const float* __restrict__ x,
    const float* __restrict__ Wf, const float* __restrict__ bf,
    const float* __restrict__ Wg, const float* __restrict__ bg,
    const float* __restrict__ Wh, const float* __restrict__ bh,
    float* __restrict__ f, float* __restrict__ g, float* __restrict__ v)
{
    __shared__ float xs[CC][64];
    const int t  = threadIdx.x;
    const int n0 = blockIdx.x * 64;
    const int b  = blockIdx.y;
    const float* xb = x + (size_t)b * CC * NN + n0;

    {
        const int j = t & 63;
        #pragma unroll
        for (int i = 0; i < 32; ++i) {
            const int c = (t >> 6) + 4 * i;
            xs[c][j] = xb[(size_t)c * NN + j];
        }
    }
    __syncthreads();

    const int jq = t & 15;   // pixel quad: j = jq*4 .. jq*4+3
    const int og = t >> 4;   // output group: o = og + 16*i

    float acc[12][4];
    #pragma unroll
    for (int i = 0; i < 12; ++i)
        #pragma unroll
        for (int jj = 0; jj < 4; ++jj) acc[i][jj] = 0.f;

    for (int c = 0; c < CC; ++c) {
        const float4 xv = *reinterpret_cast<const float4*>(&xs[c][jq * 4]);
        #pragma unroll
        for (int i = 0; i < 12; ++i) {
            const int o = og + 16 * i;
            float w;
            if (i < 2)       w = Wf[o * CC + c];
            else if (i < 4)  w = Wg[(o - 32) * CC + c];
            else             w = Wh[(o - 64) * CC + c];
            acc[i][0] += w * xv.x;
            acc[i][1] += w * xv.y;
            acc[i][2] += w * xv.z;
            acc[i][3] += w * xv.w;
        }
    }

    #pragma unroll
    for (int i = 0; i < 12; ++i) {
        const int o = og + 16 * i;
        float bias;
        float* dst;
        if (i < 2)      { bias = bf[o];      dst = f + ((size_t)b * CK + o)        * NN; }
        else if (i < 4) { bias = bg[o - 32]; dst = g + ((size_t)b * CK + (o - 32)) * NN; }
        else            { bias = bh[o - 64]; dst = v + ((size_t)b * CC + (o - 64)) * NN; }
        float4 o4;
        o4.x = acc[i][0] + bias;
        o4.y = acc[i][1] + bias;
        o4.z = acc[i][2] + bias;
        o4.w = acc[i][3] + bias;
        *reinterpret_cast<float4*>(&dst[n0 + jq * 4]) = o4;
    }
}

// ---------------------------------------------------------------------------
// Kernel 2: partial softmax denominators.
// Grid: (N/64, B, 4 m-chunks), block 256 (thread = (row n, m-subchunk ms)).
// Dpart[(b*N + n)*16 + mc*4 + ms] = sum over 256 m of exp(s[n,m])
// ---------------------------------------------------------------------------
__global__ __launch_bounds__(256) void pass1_kernel(
    const float* __restrict__ f, const float* __restrict__ g,
    float* __restrict__ Dpart)
{
    const int t  = threadIdx.x;
    const int n  = blockIdx.x * 64 + (t & 63);
    const int b  = blockIdx.y;
    const int mc = blockIdx.z;
    const int ms = t >> 6;

    const float* fb = f + (size_t)b * CK * NN;
    const float* gb = g + (size_t)b * CK * NN;

    float fr[CK];
    #pragma unroll
    for (int k = 0; k < CK; ++k) fr[k] = fb[(size_t)k * NN + n];

    const int m0 = mc * 1024 + ms * 256;
    float dacc = 0.f;
    for (int m = m0; m < m0 + 256; m += 4) {
        float s0 = 0.f, s1 = 0.f, s2 = 0.f, s3 = 0.f;
        #pragma unroll
        for (int k = 0; k < CK; ++k) {
            const float4 g4 = *reinterpret_cast<const float4*>(&gb[(size_t)k * NN + m]);
            s0 += fr[k] * g4.x;
            s1 += fr[k] * g4.y;
            s2 += fr[k] * g4.z;
            s3 += fr[k] * g4.w;
        }
        dacc += __expf(s0) + __expf(s1) + __expf(s2) + __expf(s3);
    }
    Dpart[((size_t)b * NN + n) * 16 + mc * 4 + ms] = dacc;
}

// ---------------------------------------------------------------------------
// Kernel 3: reduce partials, fold gamma and reciprocal: Dinv = gamma / D
// ---------------------------------------------------------------------------
__global__ __launch_bounds__(256) void reduce_kernel(
    const float* __restrict__ Dpart, float* __restrict__ Dinv,
    const float* __restrict__ gamma)
{
    const int i = blockIdx.x * 256 + threadIdx.x;   // over B*N
    float s = 0.f;
    #pragma unroll
    for (int q = 0; q < 4; ++q) {
        const float4 d4 = *reinterpret_cast<const float4*>(&Dpart[(size_t)i * 16 + q * 4]);
        s += d4.x + d4.y + d4.z + d4.w;
    }
    Dinv[i] = gamma[0] / s;
}

// ---------------------------------------------------------------------------
// Kernel 4: out[c,m] = sum_n (gamma*v[c,n]/D[n]) * exp(s[n,m]) + x[c,m]
// Grid: (N/64 m-tiles, B), block 256, 2 blocks/CU (66 KB LDS).
// Per n-tile: recompute exp(s) 64x64 into LDS, then 8c x 4m register-blocked PV.
// ---------------------------------------------------------------------------
__global__ __launch_bounds__(256) void pass2_kernel(
    const float* __restrict__ f, const float* __restrict__ g,
    const float* __restrict__ v, const float* __restrict__ Dinv,
    const float* __restrict__ x, float* __restrict__ out)
{
    __shared__ float fs[CK][64];
    __shared__ float gs[CK][64];
    __shared__ float ps[64][64];
    __shared__ float vs[64][132];   // pad 4 floats: keeps 16B alignment, 8-way write conflict only

    const int t   = threadIdx.x;
    const int m0g = blockIdx.x * 64;
    const int b   = blockIdx.y;

    const float* fb  = f + (size_t)b * CK * NN;
    const float* gb  = g + (size_t)b * CK * NN;
    const float* vb  = v + (size_t)b * CC * NN;
    const float* dib = Dinv + (size_t)b * NN;

    const int lane_n = t & 63;
    // load g tile once (fixed m columns for this block)
    #pragma unroll
    for (int i = 0; i < 8; ++i) {
        const int k = (t >> 6) + 4 * i;
        gs[k][lane_n] = gb[(size_t)k * NN + m0g + lane_n];
    }

    const int mq = t & 15;   // m = mq*4 .. +3
    const int co = t >> 4;   // c = co*8 .. +7
    float acc[8][4];
    #pragma unroll
    for (int ci = 0; ci < 8; ++ci)
        #pragma unroll
        for (int mi = 0; mi < 4; ++mi) acc[ci][mi] = 0.f;

    for (int nt = 0; nt < 64; ++nt) {
        const int n0 = nt * 64;
        __syncthreads();   // previous iteration fully consumed (also covers gs load)

        // stage f tile
        #pragma unroll
        for (int i = 0; i < 8; ++i) {
            const int k = (t >> 6) + 4 * i;
            fs[k][lane_n] = fb[(size_t)k * NN + n0 + lane_n];
        }
        // stage v' = gamma * v / D, transposed [n][c]
        const float di = dib[n0 + lane_n];
        #pragma unroll
        for (int i = 0; i < 32; ++i) {
            const int c = (t >> 6) + 4 * i;
            vs[lane_n][c] = vb[(size_t)c * NN + n0 + lane_n] * di;
        }
        __syncthreads();

        // s tile -> ps = exp(f^T g)
        {
            const int m   = t & 63;
            const int ng0 = (t >> 6) * 16;
            float sacc[16];
            #pragma unroll
            for (int ni = 0; ni < 16; ++ni) sacc[ni] = 0.f;
            #pragma unroll
            for (int k = 0; k < CK; ++k) {
                const float gv = gs[k][m];
                #pragma unroll
                for (int q = 0; q < 4; ++q) {
                    const float4 f4 = *reinterpret_cast<const float4*>(&fs[k][ng0 + q * 4]);
                    sacc[q * 4 + 0] += f4.x * gv;
                    sacc[q * 4 + 1] += f4.y * gv;
                    sacc[q * 4 + 2] += f4.z * gv;
                    sacc[q * 4 + 3] += f4.w * gv;
                }
            }
            #pragma unroll
            for (int ni = 0; ni < 16; ++ni)
                ps[ng0 + ni][m] = __expf(sacc[ni]);
        }
        __syncthreads();

        // PV: acc[c][m] += vs[n][c] * ps[n][m]
        #pragma unroll 2
        for (int n = 0; n < 64; ++n) {
            const float4 p4 = *reinterpret_cast<const float4*>(&ps[n][mq * 4]);
            const float4 v0 = *reinterpret_cast<const float4*>(&vs[n][co * 8]);
            const float4 v1 = *reinterpret_cast<const float4*>(&vs[n][co * 8 + 4]);
            float pv[4] = {p4.x, p4.y, p4.z, p4.w};
            float vv[8] = {v0.x, v0.y, v0.z, v0.w, v1.x, v1.y, v1.z, v1.w};
            #pragma unroll
            for (int ci = 0; ci < 8; ++ci)
                #pragma unroll
                for (int mi = 0; mi < 4; ++mi)
                    acc[ci][mi] += vv[ci] * pv[mi];
        }
    }

    // epilogue: out = acc + x (gamma already folded into Dinv)
    const float* xb = x   + (size_t)b * CC * NN;
    float*       ob = out + (size_t)b * CC * NN;
    #pragma unroll
    for (int ci = 0; ci < 8; ++ci) {
        const int c = co * 8 + ci;
        const size_t base = (size_t)c * NN + m0g + mq * 4;
        const float4 xv = *reinterpret_cast<const float4*>(&xb[base]);
        float4 o4;
        o4.x = acc[ci][0] + xv.x;
        o4.y = acc[ci][1] + xv.y;
        o4.z = acc[ci][2] + xv.z;
        o4.w = acc[ci][3] + xv.w;
        *reinterpret_cast<float4*>(&ob[base]) = o4;
    }
}

// ---------------------------------------------------------------------------
extern "C" void kernel_launch(void* const* d_in, const int* in_sizes, int n_in,
                              void* d_out, int out_size, void* d_ws, size_t ws_size,
                              hipStream_t stream)
{
    const float* x     = (const float*)d_in[0];
    const float* Wf    = (const float*)d_in[1];
    const float* bf    = (const float*)d_in[2];
    const float* Wg    = (const float*)d_in[3];
    const float* bg    = (const float*)d_in[4];
    const float* Wh    = (const float*)d_in[5];
    const float* bh    = (const float*)d_in[6];
    const float* gamma = (const float*)d_in[7];

    float* ws    = (float*)d_ws;
    float* f     = ws;                       // [B][CK][N]
    float* g     = f + (size_t)BB * CK * NN; // [B][CK][N]
    float* v     = g + (size_t)BB * CK * NN; // [B][C][N]
    float* Dpart = v + (size_t)BB * CC * NN; // [B*N][16]
    float* Dinv  = Dpart + (size_t)BB * NN * 16;

    float* out = (float*)d_out;

    proj_kernel<<<dim3(NN / 64, BB), 256, 0, stream>>>(x, Wf, bf, Wg, bg, Wh, bh, f, g, v);
    pass1_kernel<<<dim3(NN / 64, BB, 4), 256, 0, stream>>>(f, g, Dpart);
    reduce_kernel<<<dim3(BB * NN / 256), 256, 0, stream>>>(Dpart, Dinv, gamma);
    pass2_kernel<<<dim3(NN / 64, BB), 256, 0, stream>>>(f, g, v, Dinv, x, out);
}

// Round 2
// 144.587 us; speedup vs baseline: 5.0831x; 5.0831x over previous
//
#include <hip/hip_runtime.h>
#include <hip/hip_bf16.h>

#define BB 4
#define CC 128
#define NN 4096
#define CK 32
#define BM 32   // pass2 m-tile width

typedef __attribute__((ext_vector_type(8))) short short8v;
typedef __attribute__((ext_vector_type(4))) float float4v;

__device__ inline ushort f2bf(float f) {
    union { __hip_bfloat16 h; ushort u; } cv;
    cv.h = __float2bfloat16(f);
    return cv.u;
}

// ---------------------------------------------------------------------------
// Kernel 1: projections -> bf16.  ft/gt stored TRANSPOSED [b][n][32] so MFMA
// A/B fragments are contiguous 16B loads; v stored [b][c][n] bf16.
// ---------------------------------------------------------------------------
__global__ __launch_bounds__(256) void proj_kernel(
    const float* __restrict__ x,
    const float* __restrict__ Wf, const float* __restrict__ bf,
    const float* __restrict__ Wg, const float* __restrict__ bg,
    const float* __restrict__ Wh, const float* __restrict__ bh,
    ushort* __restrict__ ft, ushort* __restrict__ gt, ushort* __restrict__ vh)
{
    __shared__ float xs[CC][64];
    const int t  = threadIdx.x;
    const int n0 = blockIdx.x * 64;
    const int b  = blockIdx.y;
    const float* xb = x + (size_t)b * CC * NN + n0;

    {
        const int j = t & 63;
        #pragma unroll
        for (int i = 0; i < 32; ++i) {
            const int c = (t >> 6) + 4 * i;
            xs[c][j] = xb[(size_t)c * NN + j];
        }
    }
    __syncthreads();

    const int jq = t & 15;   // pixel quad
    const int og = t >> 4;   // output channel group

    float acc[12][4];
    #pragma unroll
    for (int i = 0; i < 12; ++i)
        #pragma unroll
        for (int jj = 0; jj < 4; ++jj) acc[i][jj] = 0.f;

    for (int c = 0; c < CC; ++c) {
        const float4 xv = *reinterpret_cast<const float4*>(&xs[c][jq * 4]);
        #pragma unroll
        for (int i = 0; i < 12; ++i) {
            const int o = og + 16 * i;
            float w;
            if (i < 2)       w = Wf[o * CC + c];
            else if (i < 4)  w = Wg[(o - 32) * CC + c];
            else             w = Wh[(o - 64) * CC + c];
            acc[i][0] += w * xv.x;
            acc[i][1] += w * xv.y;
            acc[i][2] += w * xv.z;
            acc[i][3] += w * xv.w;
        }
    }

    const int n_base = n0 + jq * 4;
    #pragma unroll
    for (int i = 0; i < 2; ++i) {
        const int o = og + 16 * i;
        const float bias = bf[o];
        #pragma unroll
        for (int jj = 0; jj < 4; ++jj)
            ft[((size_t)b * NN + n_base + jj) * CK + o] = f2bf(acc[i][jj] + bias);
    }
    #pragma unroll
    for (int i = 2; i < 4; ++i) {
        const int o = og + 16 * (i - 2);
        const float bias = bg[o];
        #pragma unroll
        for (int jj = 0; jj < 4; ++jj)
            gt[((size_t)b * NN + n_base + jj) * CK + o] = f2bf(acc[i][jj] + bias);
    }
    #pragma unroll
    for (int i = 4; i < 12; ++i) {
        const int c = og + 16 * (i - 4);
        const float bias = bh[c];
        ushort4 pk;
        pk.x = f2bf(acc[i][0] + bias);
        pk.y = f2bf(acc[i][1] + bias);
        pk.z = f2bf(acc[i][2] + bias);
        pk.w = f2bf(acc[i][3] + bias);
        *reinterpret_cast<ushort4*>(&vh[((size_t)b * CC + c) * NN + n_base]) = pk;
    }
}

// ---------------------------------------------------------------------------
// Kernel 2: partial denominators via MFMA.  Grid (N/64, B, 4 m-chunks).
// Wave w owns S rows n0+16w..+15; loops its 1024-col m-chunk in 16-col tiles.
// D-frag layout: lane l holds rows 4*(l>>4)+r, col l&15 (m89-verified).
// ---------------------------------------------------------------------------
__global__ __launch_bounds__(256) void pass1_kernel(
    const ushort* __restrict__ ft, const ushort* __restrict__ gt,
    float* __restrict__ Dpart)
{
    const int t   = threadIdx.x;
    const int w   = t >> 6;
    const int l   = t & 63;
    const int g16 = l >> 4;
    const int l16 = l & 15;
    const int n0  = blockIdx.x * 64;
    const int b   = blockIdx.y;
    const int mz  = blockIdx.z;

    const ushort* ftb = ft + (size_t)b * NN * CK;
    const ushort* gtb = gt + (size_t)b * NN * CK;

    // A fragment: A[i=l16][k=8*g16+e], rows n = n0+16w+l16
    const short8v afrag = *reinterpret_cast<const short8v*>(
        &ftb[(size_t)(n0 + 16 * w + l16) * CK + 8 * g16]);

    const float4v zf = {0.f, 0.f, 0.f, 0.f};
    float d0 = 0.f, d1 = 0.f, d2 = 0.f, d3 = 0.f;
    const int m0 = mz * 1024;
    for (int mt = 0; mt < 64; ++mt) {
        const int m = m0 + mt * 16 + l16;
        const short8v bfrag = *reinterpret_cast<const short8v*>(
            &gtb[(size_t)m * CK + 8 * g16]);
        float4v s = __builtin_amdgcn_mfma_f32_16x16x32_bf16(afrag, bfrag, zf, 0, 0, 0);
        d0 += __expf(s[0]);
        d1 += __expf(s[1]);
        d2 += __expf(s[2]);
        d3 += __expf(s[3]);
    }
    // reduce across the 16 lanes sharing g16 (masks 1,2,4,8 stay in-group)
    #pragma unroll
    for (int msk = 1; msk <= 8; msk <<= 1) {
        d0 += __shfl_xor(d0, msk);
        d1 += __shfl_xor(d1, msk);
        d2 += __shfl_xor(d2, msk);
        d3 += __shfl_xor(d3, msk);
    }
    if (l16 < 4) {
        const int n = n0 + 16 * w + 4 * g16 + l16;
        const float v = (l16 == 0) ? d0 : (l16 == 1) ? d1 : (l16 == 2) ? d2 : d3;
        Dpart[((size_t)b * NN + n) * 4 + mz] = v;
    }
}

// ---------------------------------------------------------------------------
// Kernel 3: Dinv = gamma / sum(Dpart)
// ---------------------------------------------------------------------------
__global__ __launch_bounds__(256) void reduce_kernel(
    const float* __restrict__ Dpart, float* __restrict__ Dinv,
    const float* __restrict__ gamma)
{
    const int i = blockIdx.x * 256 + threadIdx.x;   // over B*N
    const float4 d4 = *reinterpret_cast<const float4*>(&Dpart[(size_t)i * 4]);
    Dinv[i] = gamma[0] / (d4.x + d4.y + d4.z + d4.w);
}

// ---------------------------------------------------------------------------
// Kernel 4: out[c,m] = sum_n V[c,n] * (gamma*exp(s[n,m])/D[n]) + x[c,m]
// Grid (N/BM, B), 256 thr.  Stage1: S = F^T G via MFMA, scale+pack to bf16,
// transpose-write into XOR-swizzled LDS [m][n].  Stage2: PV via MFMA reading
// P as B-fragments from LDS, V as direct global 16B loads (L2-hot).
// Double-buffered P -> one barrier per n-tile.
// ---------------------------------------------------------------------------
__global__ __launch_bounds__(256) void pass2_kernel(
    const ushort* __restrict__ ft, const ushort* __restrict__ gt,
    const ushort* __restrict__ vh, const float* __restrict__ Dinv,
    const float* __restrict__ x, float* __restrict__ out)
{
    __shared__ __align__(16) ushort pss[2][BM * 64];   // [m][n] bf16, swizzled

    const int t   = threadIdx.x;
    const int w   = t >> 6;
    const int l   = t & 63;
    const int g16 = l >> 4;
    const int l16 = l & 15;
    const int m0  = blockIdx.x * BM;
    const int b   = blockIdx.y;

    const ushort* ftb = ft + (size_t)b * NN * CK;
    const ushort* gtb = gt + (size_t)b * NN * CK;
    const ushort* vhb = vh + (size_t)b * CC * NN;
    const float*  dib = Dinv + (size_t)b * NN;

    // stage-1 B fragments (g columns of this block) are loop-invariant
    short8v gfrag[2];
    #pragma unroll
    for (int tm = 0; tm < 2; ++tm)
        gfrag[tm] = *reinterpret_cast<const short8v*>(
            &gtb[(size_t)(m0 + 16 * tm + l16) * CK + 8 * g16]);

    const float4v zf = {0.f, 0.f, 0.f, 0.f};
    float4v acc[2][2];   // [tc][tm]
    #pragma unroll
    for (int tc = 0; tc < 2; ++tc)
        #pragma unroll
        for (int tm = 0; tm < 2; ++tm) acc[tc][tm] = zf;

    for (int nt = 0; nt < 64; ++nt) {
        const int n0  = nt * 64;
        const int buf = nt & 1;

        // ---- stage 1: S rows 16w..16w+15, 2 m-tiles ----
        const short8v afrag = *reinterpret_cast<const short8v*>(
            &ftb[(size_t)(n0 + 16 * w + l16) * CK + 8 * g16]);
        const float4 dinv4 = *reinterpret_cast<const float4*>(
            &dib[n0 + 16 * w + 4 * g16]);

        #pragma unroll
        for (int tm = 0; tm < 2; ++tm) {
            float4v s = __builtin_amdgcn_mfma_f32_16x16x32_bf16(afrag, gfrag[tm], zf, 0, 0, 0);
            const int ml  = 16 * tm + l16;             // P row (m-local)
            const int swz = (ml & 7) << 3;             // ushort-granule 16B XOR
            const int ub  = 16 * w + 4 * g16;          // n-local base (this lane)
            const uint p01 = ((uint)f2bf(__expf(s[0]) * dinv4.x)) |
                             ((uint)f2bf(__expf(s[1]) * dinv4.y) << 16);
            const uint p23 = ((uint)f2bf(__expf(s[2]) * dinv4.z)) |
                             ((uint)f2bf(__expf(s[3]) * dinv4.w) << 16);
            *reinterpret_cast<uint*>(&pss[buf][ml * 64 + (ub ^ swz)])       = p01;
            *reinterpret_cast<uint*>(&pss[buf][ml * 64 + ((ub + 2) ^ swz)]) = p23;
        }
        __syncthreads();   // single barrier per tile (double-buffered P)

        // ---- stage 2: PV, contraction over this tile's 64 n ----
        #pragma unroll
        for (int ks = 0; ks < 2; ++ks) {
            short8v pfrag[2];
            #pragma unroll
            for (int tm = 0; tm < 2; ++tm) {
                const int ml = 16 * tm + l16;
                const int u  = (32 * ks + 8 * g16) ^ ((ml & 7) << 3);
                pfrag[tm] = *reinterpret_cast<const short8v*>(&pss[buf][ml * 64 + u]);
            }
            #pragma unroll
            for (int tc = 0; tc < 2; ++tc) {
                const int c = 32 * w + 16 * tc + l16;
                const short8v vfrag = *reinterpret_cast<const short8v*>(
                    &vhb[(size_t)c * NN + n0 + 32 * ks + 8 * g16]);
                acc[tc][0] = __builtin_amdgcn_mfma_f32_16x16x32_bf16(vfrag, pfrag[0], acc[tc][0], 0, 0, 0);
                acc[tc][1] = __builtin_amdgcn_mfma_f32_16x16x32_bf16(vfrag, pfrag[1], acc[tc][1], 0, 0, 0);
            }
        }
    }

    // ---- epilogue: out = acc + x ----
    const float* xb = x   + (size_t)b * CC * NN;
    float*       ob = out + (size_t)b * CC * NN;
    #pragma unroll
    for (int tc = 0; tc < 2; ++tc) {
        const int c_base = 32 * w + 16 * tc + 4 * g16;
        #pragma unroll
        for (int tm = 0; tm < 2; ++tm) {
            const int m = m0 + 16 * tm + l16;
            #pragma unroll
            for (int r = 0; r < 4; ++r) {
                const size_t idx = (size_t)(c_base + r) * NN + m;
                ob[idx] = acc[tc][tm][r] + xb[idx];
            }
        }
    }
}

// ---------------------------------------------------------------------------
extern "C" void kernel_launch(void* const* d_in, const int* in_sizes, int n_in,
                              void* d_out, int out_size, void* d_ws, size_t ws_size,
                              hipStream_t stream)
{
    const float* x     = (const float*)d_in[0];
    const float* Wf    = (const float*)d_in[1];
    const float* bf    = (const float*)d_in[2];
    const float* Wg    = (const float*)d_in[3];
    const float* bg    = (const float*)d_in[4];
    const float* Wh    = (const float*)d_in[5];
    const float* bh    = (const float*)d_in[6];
    const float* gamma = (const float*)d_in[7];

    ushort* ft = (ushort*)d_ws;                    // [B][N][CK] bf16
    ushort* gt = ft + (size_t)BB * NN * CK;        // [B][N][CK] bf16
    ushort* vh = gt + (size_t)BB * NN * CK;        // [B][C][N]  bf16
    float* Dpart = (float*)(vh + (size_t)BB * CC * NN);  // [B*N][4]
    float* Dinv  = Dpart + (size_t)BB * NN * 4;          // [B*N]

    float* out = (float*)d_out;

    proj_kernel<<<dim3(NN / 64, BB), 256, 0, stream>>>(x, Wf, bf, Wg, bg, Wh, bh, ft, gt, vh);
    pass1_kernel<<<dim3(NN / 64, BB, 4), 256, 0, stream>>>(ft, gt, Dpart);
    reduce_kernel<<<dim3(BB * NN / 256), 256, 0, stream>>>(Dpart, Dinv, gamma);
    pass2_kernel<<<dim3(NN / BM, BB), 256, 0, stream>>>(ft, gt, vh, Dinv, x, out);
}

// Round 3
// 140.519 us; speedup vs baseline: 5.2302x; 1.0289x over previous
//
#include <hip/hip_runtime.h>
#include <hip/hip_bf16.h>

#define BB 4
#define CC 128
#define NN 4096
#define CK 32

typedef __attribute__((ext_vector_type(8))) short short8v;
typedef __attribute__((ext_vector_type(4))) float float4v;
typedef __attribute__((ext_vector_type(2))) unsigned int uint2v;

__device__ inline ushort f2bf(float f) {
    union { __hip_bfloat16 h; ushort u; } cv;
    cv.h = __float2bfloat16(f);
    return cv.u;
}
__device__ inline uint pk2(float lo, float hi) {
    return ((uint)f2bf(lo)) | ((uint)f2bf(hi) << 16);
}

// ---------------------------------------------------------------------------
// Kernel 1: projections -> bf16.  ft/gt stored TRANSPOSED [b][n][32] so MFMA
// A/B fragments are contiguous 16B loads; v stored [b][c][n] bf16.
// ---------------------------------------------------------------------------
__global__ __launch_bounds__(256) void proj_kernel(
    const float* __restrict__ x,
    const float* __restrict__ Wf, const float* __restrict__ bf,
    const float* __restrict__ Wg, const float* __restrict__ bg,
    const float* __restrict__ Wh, const float* __restrict__ bh,
    ushort* __restrict__ ft, ushort* __restrict__ gt, ushort* __restrict__ vh)
{
    __shared__ float xs[CC][64];
    const int t  = threadIdx.x;
    const int n0 = blockIdx.x * 64;
    const int b  = blockIdx.y;
    const float* xb = x + (size_t)b * CC * NN + n0;

    {
        const int j = t & 63;
        #pragma unroll
        for (int i = 0; i < 32; ++i) {
            const int c = (t >> 6) + 4 * i;
            xs[c][j] = xb[(size_t)c * NN + j];
        }
    }
    __syncthreads();

    const int jq = t & 15;
    const int og = t >> 4;

    float acc[12][4];
    #pragma unroll
    for (int i = 0; i < 12; ++i)
        #pragma unroll
        for (int jj = 0; jj < 4; ++jj) acc[i][jj] = 0.f;

    for (int c = 0; c < CC; ++c) {
        const float4 xv = *reinterpret_cast<const float4*>(&xs[c][jq * 4]);
        #pragma unroll
        for (int i = 0; i < 12; ++i) {
            const int o = og + 16 * i;
            float w;
            if (i < 2)       w = Wf[o * CC + c];
            else if (i < 4)  w = Wg[(o - 32) * CC + c];
            else             w = Wh[(o - 64) * CC + c];
            acc[i][0] += w * xv.x;
            acc[i][1] += w * xv.y;
            acc[i][2] += w * xv.z;
            acc[i][3] += w * xv.w;
        }
    }

    const int n_base = n0 + jq * 4;
    #pragma unroll
    for (int i = 0; i < 2; ++i) {
        const int o = og + 16 * i;
        const float bias = bf[o];
        #pragma unroll
        for (int jj = 0; jj < 4; ++jj)
            ft[((size_t)b * NN + n_base + jj) * CK + o] = f2bf(acc[i][jj] + bias);
    }
    #pragma unroll
    for (int i = 2; i < 4; ++i) {
        const int o = og + 16 * (i - 2);
        const float bias = bg[o];
        #pragma unroll
        for (int jj = 0; jj < 4; ++jj)
            gt[((size_t)b * NN + n_base + jj) * CK + o] = f2bf(acc[i][jj] + bias);
    }
    #pragma unroll
    for (int i = 4; i < 12; ++i) {
        const int c = og + 16 * (i - 4);
        const float bias = bh[c];
        ushort4 pkv;
        pkv.x = f2bf(acc[i][0] + bias);
        pkv.y = f2bf(acc[i][1] + bias);
        pkv.z = f2bf(acc[i][2] + bias);
        pkv.w = f2bf(acc[i][3] + bias);
        *reinterpret_cast<ushort4*>(&vh[((size_t)b * CC + c) * NN + n_base]) = pkv;
    }
}

// ---------------------------------------------------------------------------
// Kernel 2: partial softmax denominators via MFMA. Grid (N/64, B, 4 m-chunks).
// ---------------------------------------------------------------------------
__global__ __launch_bounds__(256) void pass1_kernel(
    const ushort* __restrict__ ft, const ushort* __restrict__ gt,
    float* __restrict__ Dpart)
{
    const int t   = threadIdx.x;
    const int w   = t >> 6;
    const int l   = t & 63;
    const int g16 = l >> 4;
    const int l16 = l & 15;
    const int n0  = blockIdx.x * 64;
    const int b   = blockIdx.y;
    const int mz  = blockIdx.z;

    const ushort* ftb = ft + (size_t)b * NN * CK;
    const ushort* gtb = gt + (size_t)b * NN * CK;

    const short8v afrag = *reinterpret_cast<const short8v*>(
        &ftb[(size_t)(n0 + 16 * w + l16) * CK + 8 * g16]);

    const float4v zf = {0.f, 0.f, 0.f, 0.f};
    float d0 = 0.f, d1 = 0.f, d2 = 0.f, d3 = 0.f;
    const int m0 = mz * 1024;
    for (int mt = 0; mt < 64; ++mt) {
        const int m = m0 + mt * 16 + l16;
        const short8v bfrag = *reinterpret_cast<const short8v*>(
            &gtb[(size_t)m * CK + 8 * g16]);
        float4v s = __builtin_amdgcn_mfma_f32_16x16x32_bf16(afrag, bfrag, zf, 0, 0, 0);
        d0 += __expf(s[0]);
        d1 += __expf(s[1]);
        d2 += __expf(s[2]);
        d3 += __expf(s[3]);
    }
    #pragma unroll
    for (int msk = 1; msk <= 8; msk <<= 1) {
        d0 += __shfl_xor(d0, msk);
        d1 += __shfl_xor(d1, msk);
        d2 += __shfl_xor(d2, msk);
        d3 += __shfl_xor(d3, msk);
    }
    if (l16 < 4) {
        const int n = n0 + 16 * w + 4 * g16 + l16;
        const float v = (l16 == 0) ? d0 : (l16 == 1) ? d1 : (l16 == 2) ? d2 : d3;
        Dpart[((size_t)b * NN + n) * 4 + mz] = v;
    }
}

// ---------------------------------------------------------------------------
// Kernel 3: Dinv = gamma / sum(Dpart)
// ---------------------------------------------------------------------------
__global__ __launch_bounds__(256) void reduce_kernel(
    const float* __restrict__ Dpart, float* __restrict__ Dinv,
    const float* __restrict__ gamma)
{
    const int i = blockIdx.x * 256 + threadIdx.x;
    const float4 d4 = *reinterpret_cast<const float4*>(&Dpart[(size_t)i * 4]);
    Dinv[i] = gamma[0] / (d4.x + d4.y + d4.z + d4.w);
}

// ---------------------------------------------------------------------------
// Kernel 4: barrier-free PV.  Block = (m-32-tile, batch); wave w = n-quarter.
// Per 32n step: 4 S-MFMAs, exp*Dinv, in-register frag relayout via
// permlane32_swap + ds_swizzle(xor16), 16 PV-MFMAs.  One __syncthreads at
// the very end to sum the 4 waves' partial accumulators through LDS.
// Grid 512 blocks (2/CU), XCD-mapped so each batch's V/f/g stay in 2 XCD L2s.
// ---------------------------------------------------------------------------
__global__ __launch_bounds__(256) void pass2_kernel(
    const ushort* __restrict__ ft, const ushort* __restrict__ gt,
    const ushort* __restrict__ vh, const float* __restrict__ Dinv,
    const float* __restrict__ x, float* __restrict__ out)
{
    __shared__ float4v rl[4][16][64];   // 64 KB: per-wave acc deposit

    const int t   = threadIdx.x;
    const int w   = t >> 6;            // wave = n-quarter
    const int l   = t & 63;
    const int g16 = l >> 4;
    const int l16 = l & 15;

    // XCD-aware mapping: xcd = bid&7 (round-robin heuristic); 2 XCDs per batch.
    const int bid  = blockIdx.x;
    const int xcd  = bid & 7;
    const int b    = xcd >> 1;
    const int m0   = ((bid >> 3) + 64 * (xcd & 1)) * 32;

    const ushort* ftb = ft + (size_t)b * NN * CK;
    const ushort* gtb = gt + (size_t)b * NN * CK;
    const ushort* vhb = vh + (size_t)b * CC * NN;
    const float*  dib = Dinv + (size_t)b * NN;

    short8v gfrag[2];
    #pragma unroll
    for (int tm = 0; tm < 2; ++tm)
        gfrag[tm] = *reinterpret_cast<const short8v*>(
            &gtb[(size_t)(m0 + 16 * tm + l16) * CK + 8 * g16]);

    const float4v zf = {0.f, 0.f, 0.f, 0.f};
    float4v acc[16];                    // fi = tc*2 + tm
    #pragma unroll
    for (int fi = 0; fi < 16; ++fi) acc[fi] = zf;

    const bool hi16 = (l & 16) != 0;

    #pragma unroll 2
    for (int it = 0; it < 32; ++it) {
        const int n0 = w * 1024 + it * 32;

        const short8v af0 = *reinterpret_cast<const short8v*>(
            &ftb[(size_t)(n0 + l16) * CK + 8 * g16]);
        const short8v af1 = *reinterpret_cast<const short8v*>(
            &ftb[(size_t)(n0 + 16 + l16) * CK + 8 * g16]);
        const float4 di0 = *reinterpret_cast<const float4*>(&dib[n0 + 4 * g16]);
        const float4 di1 = *reinterpret_cast<const float4*>(&dib[n0 + 16 + 4 * g16]);

        short8v pfrag[2];
        #pragma unroll
        for (int tm = 0; tm < 2; ++tm) {
            float4v s0 = __builtin_amdgcn_mfma_f32_16x16x32_bf16(af0, gfrag[tm], zf, 0, 0, 0);
            float4v s1 = __builtin_amdgcn_mfma_f32_16x16x32_bf16(af1, gfrag[tm], zf, 0, 0, 0);
            // P = exp(S)*Dinv, packed bf16 pairs.  a* = n-local 0..15, b* = 16..31
            const uint a0 = pk2(__expf(s0[0]) * di0.x, __expf(s0[1]) * di0.y);
            const uint a1 = pk2(__expf(s0[2]) * di0.z, __expf(s0[3]) * di0.w);
            const uint b0 = pk2(__expf(s1[0]) * di1.x, __expf(s1[1]) * di1.y);
            const uint b1 = pk2(__expf(s1[2]) * di1.z, __expf(s1[3]) * di1.w);
            // level 1: cross 32-lane halves
            const uint2v r0 = __builtin_amdgcn_permlane32_swap(a0, b0, false, false);
            const uint2v r1 = __builtin_amdgcn_permlane32_swap(a1, b1, false, false);
            // level 2: 16-group swap within halves (ds_swizzle xor 16 + select)
            const uint sA0 = (uint)__builtin_amdgcn_ds_swizzle((int)r0[0], 0x401F);
            const uint sB0 = (uint)__builtin_amdgcn_ds_swizzle((int)r0[1], 0x401F);
            const uint sA1 = (uint)__builtin_amdgcn_ds_swizzle((int)r1[0], 0x401F);
            const uint sB1 = (uint)__builtin_amdgcn_ds_swizzle((int)r1[1], 0x401F);
            union { uint u[4]; short8v s; } pf;
            pf.u[0] = hi16 ? sB0 : r0[0];   // n = 8g16+0,1
            pf.u[1] = hi16 ? sB1 : r1[0];   // n = 8g16+2,3
            pf.u[2] = hi16 ? r0[1] : sA0;   // n = 8g16+4,5
            pf.u[3] = hi16 ? r1[1] : sA1;   // n = 8g16+6,7
            pfrag[tm] = pf.s;
        }

        #pragma unroll
        for (int tc = 0; tc < 8; ++tc) {
            const short8v vf = *reinterpret_cast<const short8v*>(
                &vhb[(size_t)(16 * tc + l16) * NN + n0 + 8 * g16]);
            acc[tc * 2 + 0] = __builtin_amdgcn_mfma_f32_16x16x32_bf16(vf, pfrag[0], acc[tc * 2 + 0], 0, 0, 0);
            acc[tc * 2 + 1] = __builtin_amdgcn_mfma_f32_16x16x32_bf16(vf, pfrag[1], acc[tc * 2 + 1], 0, 0, 0);
        }
    }

    // deposit all waves' partials, one barrier, quarter-reduce per wave
    #pragma unroll
    for (int fi = 0; fi < 16; ++fi) rl[w][fi][l] = acc[fi];
    __syncthreads();

    const float* xb = x   + (size_t)b * CC * NN;
    float*       ob = out + (size_t)b * CC * NN;
    #pragma unroll
    for (int ii = 0; ii < 4; ++ii) {
        const int fi = w * 4 + ii;
        float4v s = rl[0][fi][l] + rl[1][fi][l] + rl[2][fi][l] + rl[3][fi][l];
        const int tc = fi >> 1, tm = fi & 1;
        const int m  = m0 + 16 * tm + l16;
        const int cb = 16 * tc + 4 * g16;
        #pragma unroll
        for (int r = 0; r < 4; ++r) {
            const size_t idx = (size_t)(cb + r) * NN + m;
            ob[idx] = s[r] + xb[idx];
        }
    }
}

// ---------------------------------------------------------------------------
extern "C" void kernel_launch(void* const* d_in, const int* in_sizes, int n_in,
                              void* d_out, int out_size, void* d_ws, size_t ws_size,
                              hipStream_t stream)
{
    const float* x     = (const float*)d_in[0];
    const float* Wf    = (const float*)d_in[1];
    const float* bf    = (const float*)d_in[2];
    const float* Wg    = (const float*)d_in[3];
    const float* bg    = (const float*)d_in[4];
    const float* Wh    = (const float*)d_in[5];
    const float* bh    = (const float*)d_in[6];
    const float* gamma = (const float*)d_in[7];

    ushort* ft = (ushort*)d_ws;                    // [B][N][CK] bf16
    ushort* gt = ft + (size_t)BB * NN * CK;        // [B][N][CK] bf16
    ushort* vh = gt + (size_t)BB * NN * CK;        // [B][C][N]  bf16
    float* Dpart = (float*)(vh + (size_t)BB * CC * NN);  // [B*N][4]
    float* Dinv  = Dpart + (size_t)BB * NN * 4;          // [B*N]

    float* out = (float*)d_out;

    proj_kernel<<<dim3(NN / 64, BB), 256, 0, stream>>>(x, Wf, bf, Wg, bg, Wh, bh, ft, gt, vh);
    pass1_kernel<<<dim3(NN / 64, BB, 4), 256, 0, stream>>>(ft, gt, Dpart);
    reduce_kernel<<<dim3(BB * NN / 256), 256, 0, stream>>>(Dpart, Dinv, gamma);
    pass2_kernel<<<dim3(512), 256, 0, stream>>>(ft, gt, vh, Dinv, x, out);
}

// Round 5
// 124.428 us; speedup vs baseline: 5.9066x; 1.1293x over previous
//
#include <hip/hip_runtime.h>
#include <hip/hip_bf16.h>

#define BB 4
#define CC 128
#define NN 4096
#define CK 32
#define L2E 1.442695040888963f

typedef __attribute__((ext_vector_type(8))) short short8v;
typedef __attribute__((ext_vector_type(4))) float float4v;
typedef __attribute__((ext_vector_type(2))) unsigned int uint2v;

__device__ inline ushort f2bf(float f) {
    union { __hip_bfloat16 h; ushort u; } cv;
    cv.h = __float2bfloat16(f);
    return cv.u;
}
__device__ inline uint pk2(float lo, float hi) {
    return ((uint)f2bf(lo)) | ((uint)f2bf(hi) << 16);
}

// ---------------------------------------------------------------------------
// Kernel 1: projections -> bf16.  ft/gt [b][n][32] (MFMA-fragment-contiguous),
// v [b][c][n] with sign(gamma) folded in.
// ---------------------------------------------------------------------------
__global__ __launch_bounds__(256) void proj_kernel(
    const float* __restrict__ x,
    const float* __restrict__ Wf, const float* __restrict__ bf,
    const float* __restrict__ Wg, const float* __restrict__ bg,
    const float* __restrict__ Wh, const float* __restrict__ bh,
    const float* __restrict__ gamma,
    ushort* __restrict__ ft, ushort* __restrict__ gt, ushort* __restrict__ vh)
{
    __shared__ float xs[CC][64];
    const int t  = threadIdx.x;
    const int n0 = blockIdx.x * 64;
    const int b  = blockIdx.y;
    const float* xb = x + (size_t)b * CC * NN + n0;

    {
        const int j = t & 63;
        #pragma unroll
        for (int i = 0; i < 32; ++i) {
            const int c = (t >> 6) + 4 * i;
            xs[c][j] = xb[(size_t)c * NN + j];
        }
    }
    __syncthreads();

    const int jq = t & 15;
    const int og = t >> 4;

    float acc[12][4];
    #pragma unroll
    for (int i = 0; i < 12; ++i)
        #pragma unroll
        for (int jj = 0; jj < 4; ++jj) acc[i][jj] = 0.f;

    for (int c = 0; c < CC; ++c) {
        const float4 xv = *reinterpret_cast<const float4*>(&xs[c][jq * 4]);
        #pragma unroll
        for (int i = 0; i < 12; ++i) {
            const int o = og + 16 * i;
            float w;
            if (i < 2)       w = Wf[o * CC + c];
            else if (i < 4)  w = Wg[(o - 32) * CC + c];
            else             w = Wh[(o - 64) * CC + c];
            acc[i][0] += w * xv.x;
            acc[i][1] += w * xv.y;
            acc[i][2] += w * xv.z;
            acc[i][3] += w * xv.w;
        }
    }

    const float sgn = (gamma[0] < 0.f) ? -1.f : 1.f;
    const int n_base = n0 + jq * 4;
    #pragma unroll
    for (int i = 0; i < 2; ++i) {
        const int o = og + 16 * i;
        const float bias = bf[o];
        #pragma unroll
        for (int jj = 0; jj < 4; ++jj)
            ft[((size_t)b * NN + n_base + jj) * CK + o] = f2bf(acc[i][jj] + bias);
    }
    #pragma unroll
    for (int i = 2; i < 4; ++i) {
        const int o = og + 16 * (i - 2);
        const float bias = bg[o];
        #pragma unroll
        for (int jj = 0; jj < 4; ++jj)
            gt[((size_t)b * NN + n_base + jj) * CK + o] = f2bf(acc[i][jj] + bias);
    }
    #pragma unroll
    for (int i = 4; i < 12; ++i) {
        const int c = og + 16 * (i - 4);
        const float bias = bh[c];
        ushort4 pkv;
        pkv.x = f2bf(sgn * (acc[i][0] + bias));
        pkv.y = f2bf(sgn * (acc[i][1] + bias));
        pkv.z = f2bf(sgn * (acc[i][2] + bias));
        pkv.w = f2bf(sgn * (acc[i][3] + bias));
        *reinterpret_cast<ushort4*>(&vh[((size_t)b * CC + c) * NN + n_base]) = pkv;
    }
}

// ---------------------------------------------------------------------------
// Kernel 2: partial softmax denominators via MFMA, double-buffered b-frags.
// Grid (N/64, B, 4 m-chunks).
// ---------------------------------------------------------------------------
__global__ __launch_bounds__(256) void pass1_kernel(
    const ushort* __restrict__ ft, const ushort* __restrict__ gt,
    float* __restrict__ Dpart)
{
    const int t   = threadIdx.x;
    const int w   = t >> 6;
    const int l   = t & 63;
    const int g16 = l >> 4;
    const int l16 = l & 15;
    const int n0  = blockIdx.x * 64;
    const int b   = blockIdx.y;
    const int mz  = blockIdx.z;

    const ushort* ftb = ft + (size_t)b * NN * CK;
    const ushort* gtb = gt + (size_t)b * NN * CK;

    const short8v afrag = *reinterpret_cast<const short8v*>(
        &ftb[(size_t)(n0 + 16 * w + l16) * CK + 8 * g16]);

    const float4v zf = {0.f, 0.f, 0.f, 0.f};
    float d0 = 0.f, d1 = 0.f, d2 = 0.f, d3 = 0.f;
    const int m0 = mz * 1024;

    short8v bfA = *reinterpret_cast<const short8v*>(
        &gtb[(size_t)(m0 + l16) * CK + 8 * g16]);
    #pragma unroll 1
    for (int mt = 0; mt < 64; mt += 2) {
        const short8v bfB = *reinterpret_cast<const short8v*>(
            &gtb[(size_t)(m0 + (mt + 1) * 16 + l16) * CK + 8 * g16]);
        float4v s = __builtin_amdgcn_mfma_f32_16x16x32_bf16(afrag, bfA, zf, 0, 0, 0);
        d0 += __expf(s[0]); d1 += __expf(s[1]); d2 += __expf(s[2]); d3 += __expf(s[3]);
        bfA = *reinterpret_cast<const short8v*>(
            &gtb[(size_t)(m0 + (((mt + 2) & 63)) * 16 + l16) * CK + 8 * g16]);
        float4v s2 = __builtin_amdgcn_mfma_f32_16x16x32_bf16(afrag, bfB, zf, 0, 0, 0);
        d0 += __expf(s2[0]); d1 += __expf(s2[1]); d2 += __expf(s2[2]); d3 += __expf(s2[3]);
    }
    #pragma unroll
    for (int msk = 1; msk <= 8; msk <<= 1) {
        d0 += __shfl_xor(d0, msk);
        d1 += __shfl_xor(d1, msk);
        d2 += __shfl_xor(d2, msk);
        d3 += __shfl_xor(d3, msk);
    }
    if (l16 < 4) {
        const int n = n0 + 16 * w + 4 * g16 + l16;
        const float v = (l16 == 0) ? d0 : (l16 == 1) ? d1 : (l16 == 2) ? d2 : d3;
        Dpart[((size_t)b * NN + n) * 4 + mz] = v;
    }
}

// ---------------------------------------------------------------------------
// Kernel 3: Ld = log2(|gamma| / D)   (sign of gamma folded into V)
// ---------------------------------------------------------------------------
__global__ __launch_bounds__(256) void reduce_kernel(
    const float* __restrict__ Dpart, float* __restrict__ Ld,
    const float* __restrict__ gamma)
{
    const int i = blockIdx.x * 256 + threadIdx.x;
    const float4 d4 = *reinterpret_cast<const float4*>(&Dpart[(size_t)i * 4]);
    const float D = d4.x + d4.y + d4.z + d4.w;
    Ld[i] = log2f(fabsf(gamma[0])) - log2f(D);
}

// ---------------------------------------------------------------------------
// Kernel 4: barrier-free PV with explicit double-buffered prefetch.
// P = exp2(S*log2e + Ld[n]) packed bf16; in-register frag relayout via
// permlane32_swap + ds_swizzle(xor16); 16 PV-MFMAs.  One final LDS reduce.
// ---------------------------------------------------------------------------
__global__ __launch_bounds__(256, 2) void pass2_kernel(
    const ushort* __restrict__ ft, const ushort* __restrict__ gt,
    const ushort* __restrict__ vh, const float* __restrict__ Ld,
    const float* __restrict__ x, float* __restrict__ out)
{
    __shared__ float4v rl[4][16][64];   // 64 KB final-reduce deposit

    const int t   = threadIdx.x;
    const int w   = t >> 6;            // wave = n-quarter
    const int l   = t & 63;
    const int g16 = l >> 4;
    const int l16 = l & 15;

    const int bid = blockIdx.x;
    const int xcd = bid & 7;
    const int b   = xcd >> 1;
    const int m0  = ((bid >> 3) + 64 * (xcd & 1)) * 32;

    const ushort* ftb = ft + (size_t)b * NN * CK;
    const ushort* gtb = gt + (size_t)b * NN * CK;
    const ushort* vhb = vh + (size_t)b * CC * NN;
    const float*  ldb = Ld + (size_t)b * NN;

    const short8v gfrag0 = *reinterpret_cast<const short8v*>(
        &gtb[(size_t)(m0 + l16) * CK + 8 * g16]);
    const short8v gfrag1 = *reinterpret_cast<const short8v*>(
        &gtb[(size_t)(m0 + 16 + l16) * CK + 8 * g16]);

    const float4v zf = {0.f, 0.f, 0.f, 0.f};
    float4v acc[16];
    #pragma unroll
    for (int fi = 0; fi < 16; ++fi) acc[fi] = zf;

    const bool hi16 = (l & 16) != 0;
    const int nb = w * 1024;

    short8v afA[2], afB[2], vfA[8], vfB[8];
    float4  ldA[2], ldB[2];

#define LOADIT(AF, LDV, VF, n0_) do {                                          \
    _Pragma("unroll")                                                          \
    for (int q = 0; q < 2; ++q) {                                              \
        AF[q] = *reinterpret_cast<const short8v*>(                             \
            &ftb[(size_t)((n0_) + 16 * q + l16) * CK + 8 * g16]);              \
        LDV[q] = *reinterpret_cast<const float4*>(                             \
            &ldb[(n0_) + 16 * q + 4 * g16]);                                   \
    }                                                                          \
    _Pragma("unroll")                                                          \
    for (int tc = 0; tc < 8; ++tc)                                             \
        VF[tc] = *reinterpret_cast<const short8v*>(                            \
            &vhb[(size_t)(16 * tc + l16) * NN + (n0_) + 8 * g16]);             \
} while (0)

#define COMPUTE(AF, LDV, VF) do {                                              \
    short8v pfr[2];                                                            \
    _Pragma("unroll")                                                          \
    for (int tm = 0; tm < 2; ++tm) {                                           \
        const short8v gg = tm ? gfrag1 : gfrag0;                               \
        float4v s0 = __builtin_amdgcn_mfma_f32_16x16x32_bf16(AF[0], gg, zf, 0, 0, 0); \
        float4v s1 = __builtin_amdgcn_mfma_f32_16x16x32_bf16(AF[1], gg, zf, 0, 0, 0); \
        const uint a0 = pk2(__builtin_amdgcn_exp2f(fmaf(s0[0], L2E, LDV[0].x)), \
                            __builtin_amdgcn_exp2f(fmaf(s0[1], L2E, LDV[0].y))); \
        const uint a1 = pk2(__builtin_amdgcn_exp2f(fmaf(s0[2], L2E, LDV[0].z)), \
                            __builtin_amdgcn_exp2f(fmaf(s0[3], L2E, LDV[0].w))); \
        const uint b0 = pk2(__builtin_amdgcn_exp2f(fmaf(s1[0], L2E, LDV[1].x)), \
                            __builtin_amdgcn_exp2f(fmaf(s1[1], L2E, LDV[1].y))); \
        const uint b1 = pk2(__builtin_amdgcn_exp2f(fmaf(s1[2], L2E, LDV[1].z)), \
                            __builtin_amdgcn_exp2f(fmaf(s1[3], L2E, LDV[1].w))); \
        const uint2v r0 = __builtin_amdgcn_permlane32_swap(a0, b0, false, false); \
        const uint2v r1 = __builtin_amdgcn_permlane32_swap(a1, b1, false, false); \
        const uint sA0 = (uint)__builtin_amdgcn_ds_swizzle((int)r0[0], 0x401F); \
        const uint sB0 = (uint)__builtin_amdgcn_ds_swizzle((int)r0[1], 0x401F); \
        const uint sA1 = (uint)__builtin_amdgcn_ds_swizzle((int)r1[0], 0x401F); \
        const uint sB1 = (uint)__builtin_amdgcn_ds_swizzle((int)r1[1], 0x401F); \
        union { uint u[4]; short8v s; } pf;                                    \
        pf.u[0] = hi16 ? sB0 : r0[0];                                          \
        pf.u[1] = hi16 ? sB1 : r1[0];                                          \
        pf.u[2] = hi16 ? r0[1] : sA0;                                          \
        pf.u[3] = hi16 ? r1[1] : sA1;                                          \
        pfr[tm] = pf.s;                                                        \
    }                                                                          \
    _Pragma("unroll")                                                          \
    for (int tc = 0; tc < 8; ++tc) {                                           \
        acc[tc * 2 + 0] = __builtin_amdgcn_mfma_f32_16x16x32_bf16(VF[tc], pfr[0], acc[tc * 2 + 0], 0, 0, 0); \
        acc[tc * 2 + 1] = __builtin_amdgcn_mfma_f32_16x16x32_bf16(VF[tc], pfr[1], acc[tc * 2 + 1], 0, 0, 0); \
    }                                                                          \
} while (0)

    LOADIT(afA, ldA, vfA, nb);
    #pragma unroll 1
    for (int it = 0; it < 32; it += 2) {
        LOADIT(afB, ldB, vfB, nb + ((it + 1) & 31) * 32);
        COMPUTE(afA, ldA, vfA);
        LOADIT(afA, ldA, vfA, nb + ((it + 2) & 31) * 32);
        COMPUTE(afB, ldB, vfB);
    }
#undef LOADIT
#undef COMPUTE

    // deposit all waves' partials, one barrier, quarter-reduce per wave
    #pragma unroll
    for (int fi = 0; fi < 16; ++fi) rl[w][fi][l] = acc[fi];
    __syncthreads();

    const float* xb = x   + (size_t)b * CC * NN;
    float*       ob = out + (size_t)b * CC * NN;
    #pragma unroll
    for (int ii = 0; ii < 4; ++ii) {
        const int fi = w * 4 + ii;
        float4v s = rl[0][fi][l] + rl[1][fi][l] + rl[2][fi][l] + rl[3][fi][l];
        const int tc = fi >> 1, tm = fi & 1;
        const int m  = m0 + 16 * tm + l16;
        const int cb = 16 * tc + 4 * g16;
        #pragma unroll
        for (int r = 0; r < 4; ++r) {
            const size_t idx = (size_t)(cb + r) * NN + m;
            ob[idx] = s[r] + xb[idx];
        }
    }
}

// ---------------------------------------------------------------------------
extern "C" void kernel_launch(void* const* d_in, const int* in_sizes, int n_in,
                              void* d_out, int out_size, void* d_ws, size_t ws_size,
                              hipStream_t stream)
{
    const float* x     = (const float*)d_in[0];
    const float* Wf    = (const float*)d_in[1];
    const float* bf    = (const float*)d_in[2];
    const float* Wg    = (const float*)d_in[3];
    const float* bg    = (const float*)d_in[4];
    const float* Wh    = (const float*)d_in[5];
    const float* bh    = (const float*)d_in[6];
    const float* gamma = (const float*)d_in[7];

    ushort* ft = (ushort*)d_ws;                    // [B][N][CK] bf16
    ushort* gt = ft + (size_t)BB * NN * CK;        // [B][N][CK] bf16
    ushort* vh = gt + (size_t)BB * NN * CK;        // [B][C][N]  bf16 (sign-folded)
    float* Dpart = (float*)(vh + (size_t)BB * CC * NN);  // [B*N][4]
    float* Ld    = Dpart + (size_t)BB * NN * 4;          // [B*N] log2(|g|/D)

    float* out = (float*)d_out;

    proj_kernel<<<dim3(NN / 64, BB), 256, 0, stream>>>(x, Wf, bf, Wg, bg, Wh, bh, gamma, ft, gt, vh);
    pass1_kernel<<<dim3(NN / 64, BB, 4), 256, 0, stream>>>(ft, gt, Dpart);
    reduce_kernel<<<dim3(BB * NN / 256), 256, 0, stream>>>(Dpart, Ld, gamma);
    pass2_kernel<<<dim3(512), 256, 0, stream>>>(ft, gt, vh, Ld, x, out);
}